// Round 14
// baseline (70.288 us; speedup 1.0000x reference)
//
#include <hip/hip_runtime.h>

#define QLEN 1024
#define KLEN 1024
#define BSZ 2
#define NHEAD 16
#define DHEAD 64
#define RS 2048            /* BSZ*NHEAD*DHEAD floats per seq row */
#define BLK_I 64
#define BLK_J 32
#define NT32 (KLEN / BLK_J)   /* 32 tiles per bn */
#define NBN (BSZ * NHEAD)

#define SC2f  0.18033688011112440f   /* 0.125 * log2(e) */
#define MBIGf 1.4426950408889634e30f /* 1e30 * log2(e)  */

#define SEGP_BYTES  16777216u                     /* BSZ*QLEN*KLEN*8  */
#define KT_BYTES    ((size_t)NBN * NT32 * 4096)   /* 4 MiB per tensor */

typedef __attribute__((ext_vector_type(8))) short s16x8;
typedef __attribute__((ext_vector_type(8))) unsigned short u16x8;
typedef __attribute__((ext_vector_type(4))) unsigned short u16x4;
typedef __attribute__((ext_vector_type(4))) float f32x4;
typedef __attribute__((ext_vector_type(2))) float f32x2;

__device__ __forceinline__ unsigned short f2bf(float f) {
    union { float f; unsigned int u; } x; x.f = f;
    unsigned int r = x.u + 0x7fffu + ((x.u >> 16) & 1u);
    return (unsigned short)(r >> 16);
}
__device__ __forceinline__ float bf2f(unsigned short h) {
    union { unsigned int u; float f; } x; x.u = ((unsigned int)h) << 16;
    return x.f;
}

typedef const __attribute__((address_space(1))) unsigned int* gas_t;
typedef __attribute__((address_space(3))) unsigned int* las_t;
__device__ __forceinline__ void gl_lds16(const void* g, void* l) {
    __builtin_amdgcn_global_load_lds((gas_t)g, (las_t)l, 16, 0, 0);
}

// ---- fused pre-pass (verbatim round-12/13, passed) --------------------------
__global__ __launch_bounds__(256)
void pack_all_kernel(const float* __restrict__ segmat,
                     const float* __restrict__ mask,
                     const float* __restrict__ kh,
                     const float* __restrict__ kr,
                     const float* __restrict__ v,
                     u16x4* __restrict__ segP,
                     unsigned short* __restrict__ Kp,
                     unsigned short* __restrict__ Krp,
                     unsigned short* __restrict__ Vtp)
{
    __shared__ float VT[32][65];
    const int bid = blockIdx.x;
    const int tid = threadIdx.x;

    if (bid < 1024) {
        const int gid = bid * 256 + tid;          // BSZ*QLEN*KLEN/8 items
        const int j8  = gid & (KLEN / 8 - 1);
        const int i   = (gid >> 7) & (QLEN - 1);
        const int b   = gid >> 17;
        const float* sp = segmat + ((size_t)(i * KLEN + j8 * 8) * BSZ + b) * 2;
        const float* mp = mask + (size_t)i * KLEN + j8 * 8;
        u16x4* op = segP + (size_t)(b * QLEN + i) * KLEN + j8 * 8;
#pragma unroll
        for (int e = 0; e < 8; ++e) {
            const f32x2 sm = *(const f32x2*)(sp + e * (BSZ * 2));
            u16x4 pk;
            pk[0] = f2bf(sm[0]); pk[1] = f2bf(sm[1]);
            pk[2] = f2bf(mp[e] * MBIGf); pk[3] = 0;
            op[e] = pk;
        }
    } else {
        const int blk = bid - 1024;               // bn*NT32 + jt
        const int bn  = blk >> 5;
        const int jt  = blk & (NT32 - 1);
        const int b   = bn & 1;
        const int n   = bn >> 1;
        const int boff = b * NHEAD * DHEAD + n * DHEAD;
        const int j0  = jt * BLK_J;

        {   // v tile -> LDS (coalesced): 32 j-rows x 64 d
            const int j  = tid >> 3;
            const int dq = (tid & 7) * 8;
            const float* vp = v + (size_t)(j0 + j) * RS + boff + dq;
#pragma unroll
            for (int e = 0; e < 8; ++e) VT[j][dq + e] = vp[e];
        }
        __syncthreads();

        const size_t tb = (size_t)blk * 2048;     // u16 units (4KB tiles)
        {   // K / Kr: 256 chunks of 16B; row = j (0..31), 8 chunks/row
            const int row = tid >> 3;
            const int ch  = (tid & 7) ^ (row & 7);
            u16x8 ok, orr;
            const float* hp = kh + (size_t)(j0 + row) * RS + boff + ch * 8;
            const float* rp = kr + (size_t)(j0 + row + 1) * RS + boff + ch * 8; // shift +1
#pragma unroll
            for (int e = 0; e < 8; ++e) { ok[e] = f2bf(hp[e]); orr[e] = f2bf(rp[e]); }
            *(u16x8*)&Kp [tb + (size_t)tid * 8] = ok;
            *(u16x8*)&Krp[tb + (size_t)tid * 8] = orr;
        }
        {   // V^T: 256 granules; row = d (0..63), 4 granules/row
            const int d  = tid >> 2;
            const int g  = tid & 3;
            const int ch = g ^ (d & 3);
            u16x8 ov;
#pragma unroll
            for (int e = 0; e < 8; ++e) ov[e] = f2bf(VT[ch * 8 + e][d]);
            *(u16x8*)&Vtp[tb + (size_t)tid * 8] = ov;
        }
    }
}

// ---- main: swapped-QK + counted-vmcnt pipeline (T4), seg prefetch d=1 -------
__global__ __launch_bounds__(256, 2)
void relattn_kernel(const float* __restrict__ q,
                    const float* __restrict__ segemb,
                    const float* __restrict__ rwb,
                    const float* __restrict__ rrb,
                    const float* __restrict__ rsb,
                    const u16x4* __restrict__ segP,
                    const unsigned short* __restrict__ Kp,
                    const unsigned short* __restrict__ Krp,
                    const unsigned short* __restrict__ Vtp,
                    float* __restrict__ out)
{
    __shared__ unsigned short KhL[2][32][64];
    __shared__ unsigned short KrL[2][32][64];
    __shared__ unsigned short VtL[2][64][32];
    __shared__ unsigned short PlP[4][16][40];   // per-wave P^T xchg (5KB)

    // XCD swizzle (R13, kept: FETCH 62->37MB): group 16 heads of one (b,i0)
    const int F = blockIdx.x;            // 512 blocks
    const int x = F & 7;
    const int k = F >> 3;                // 0..63
    const int g = (k >> 4) * 8 + x;      // (b,i0) group id, 4 groups per XCD
    const int i0 = (g >> 1) * BLK_I;
    const int b  = g & 1;
    const int n  = k & 15;
    const int bn = n * 2 + b;            // matches pack layout
    const int boff = b * NHEAD * DHEAD + n * DHEAD;

    const int tid  = threadIdx.x;
    const int wave = tid >> 6;
    const int lane = tid & 63;
    const int q4   = lane >> 4;
    const int c    = lane & 15;
    const int iRow = i0 + wave * 16 + c;

    // ---- Q fragments + in-lane ef0 ----
    s16x8 qwf[2], qrf[2];
    float e0, e1;
    {
        const float* qp = q + (size_t)iRow * RS + boff;
        float es0 = 0.f, es1 = 0.f;
#pragma unroll
        for (int kk = 0; kk < 2; ++kk) {
            const int off = kk * 32 + q4 * 8;
            const f32x4 q0 = *(const f32x4*)(qp + off);
            const f32x4 q1 = *(const f32x4*)(qp + off + 4);
            const f32x4 w0 = *(const f32x4*)(rwb + n * DHEAD + off);
            const f32x4 w1 = *(const f32x4*)(rwb + n * DHEAD + off + 4);
            const f32x4 r0 = *(const f32x4*)(rrb + n * DHEAD + off);
            const f32x4 r1 = *(const f32x4*)(rrb + n * DHEAD + off + 4);
            const f32x4 sa = *(const f32x4*)(segemb + n * DHEAD + off);
            const f32x4 sb = *(const f32x4*)(segemb + n * DHEAD + off + 4);
            const f32x4 ta = *(const f32x4*)(segemb + (NHEAD + n) * DHEAD + off);
            const f32x4 tb = *(const f32x4*)(segemb + (NHEAD + n) * DHEAD + off + 4);
            const f32x4 ra = *(const f32x4*)(rsb + n * DHEAD + off);
            const f32x4 rb = *(const f32x4*)(rsb + n * DHEAD + off + 4);
            s16x8 tw, tr;
#pragma unroll
            for (int e = 0; e < 4; ++e) {
                tw[e]     = (short)f2bf(q0[e] + w0[e]);
                tw[4 + e] = (short)f2bf(q1[e] + w1[e]);
                tr[e]     = (short)f2bf(q0[e] + r0[e]);
                tr[4 + e] = (short)f2bf(q1[e] + r1[e]);
                es0 += (q0[e] + ra[e]) * sa[e] + (q1[e] + rb[e]) * sb[e];
                es1 += (q0[e] + ra[e]) * ta[e] + (q1[e] + rb[e]) * tb[e];
            }
            qwf[kk] = tw; qrf[kk] = tr;
        }
        es0 += __shfl_xor(es0, 16, 64); es0 += __shfl_xor(es0, 32, 64);
        es1 += __shfl_xor(es1, 16, 64); es1 += __shfl_xor(es1, 32, 64);
        e0 = es0 * SC2f; e1 = es1 * SC2f;
    }

    const int tbase = bn * NT32;
    auto stage = [&](int jt, int buf) {
        const size_t toff = ((size_t)(tbase + jt)) << 12;
        const int go = tid * 16;
        const int lo = wave * 1024;
        gl_lds16((const char*)Kp  + toff + go, (char*)&KhL[buf][0][0] + lo);
        gl_lds16((const char*)Krp + toff + go, (char*)&KrL[buf][0][0] + lo);
        gl_lds16((const char*)Vtp + toff + go, (char*)&VtL[buf][0][0] + lo);
    };
    const u16x4* spB = segP + (size_t)b * QLEN * KLEN;
    auto segload = [&](int jt, u16x8 (&pg)[2][2]) {
        const u16x4* pp = spB + (size_t)iRow * KLEN + jt * BLK_J + q4 * 4;
        pg[0][0] = *(const u16x8*)pp;
        pg[0][1] = *(const u16x8*)(pp + 2);
        pg[1][0] = *(const u16x8*)(pp + 16);
        pg[1][1] = *(const u16x8*)(pp + 18);
    };

    float m = -INFINITY, lsum = 0.f;
    f32x4 acc[4];
#pragma unroll
    for (int dt = 0; dt < 4; ++dt) acc[dt] = (f32x4)0.f;

    // ---- prologue: tile 0 staged, seg(0) in flight; drain only the DMA ----
    u16x8 pgA[2][2], pgB[2][2];
    stage(0, 0);                                  // 3 DMA (issued first)
    __builtin_amdgcn_sched_barrier(0);
    segload(0, pgA);                              // 4 loads (issued last)
    __builtin_amdgcn_sched_barrier(0);
    asm volatile("s_waitcnt vmcnt(4)" ::: "memory");   // newest 4 = seg(0) stay in flight
    __builtin_amdgcn_s_barrier();
    __builtin_amdgcn_sched_barrier(0);

    // ---- iteration body: stage(t+1) + segload(t+1) early; counted drain ----
    auto body = [&](int t, int bufc, u16x8 (&pgC)[2][2], u16x8 (&pgN)[2][2]) {
        const int tn = (t + 1 < NT32) ? t + 1 : NT32 - 1;   // clamp: constant op count
        stage(tn, bufc ^ 1);                      // 3 DMA for next tile
        __builtin_amdgcn_sched_barrier(0);
        segload(tn, pgN);                         // 4 seg loads for next tile
        __builtin_amdgcn_sched_barrier(0);

        // ---- S^T = (Kh Qw^T + Kr Qr^T) on buf[bufc] ----
        f32x4 sjT[2];
        sjT[0] = (f32x4)0.f; sjT[1] = (f32x4)0.f;
        __builtin_amdgcn_s_setprio(1);
#pragma unroll
        for (int kk = 0; kk < 2; ++kk)
#pragma unroll
            for (int js = 0; js < 2; ++js) {
                const int row = js * 16 + c;
                const int pcK = ((kk * 4 + q4) ^ (c & 7)) * 8;
                const s16x8 khf = *(const s16x8*)&KhL[bufc][row][pcK];
                const s16x8 krf = *(const s16x8*)&KrL[bufc][row][pcK];
                sjT[js] = __builtin_amdgcn_mfma_f32_16x16x32_bf16(khf, qwf[kk], sjT[js], 0, 0, 0);
                sjT[js] = __builtin_amdgcn_mfma_f32_16x16x32_bf16(krf, qrf[kk], sjT[js], 0, 0, 0);
            }
        __builtin_amdgcn_s_setprio(0);

        // ---- bias (seg regs prefetched last iter) + lane-local softmax ----
        float sc8[8];
#pragma unroll
        for (int js = 0; js < 2; ++js)
#pragma unroll
            for (int r = 0; r < 4; ++r) {
                const u16x8 g2 = pgC[js][r >> 1];
                const int bb = (r & 1) * 4;
                sc8[js * 4 + r] = sjT[js][r] * SC2f
                                  + bf2f(g2[bb]) * e0 + bf2f(g2[bb + 1]) * e1
                                  - bf2f(g2[bb + 2]);
            }
        float mt = fmaxf(
            fmaxf(fmaxf(sc8[0], sc8[1]), fmaxf(sc8[2], sc8[3])),
            fmaxf(fmaxf(sc8[4], sc8[5]), fmaxf(sc8[6], sc8[7])));
        mt = fmaxf(mt, __shfl_xor(mt, 16, 64));
        mt = fmaxf(mt, __shfl_xor(mt, 32, 64));
        const float mn  = fmaxf(m, mt);
        const float scl = __builtin_amdgcn_exp2f(m - mn);
        m = mn;
#pragma unroll
        for (int dt = 0; dt < 4; ++dt) acc[dt] *= scl;
        float p[8], ps = 0.f;
#pragma unroll
        for (int e = 0; e < 8; ++e) {
            p[e] = __builtin_amdgcn_exp2f(sc8[e] - m);
            ps += p[e];
        }
        lsum = lsum * scl + ps;

        // ---- pack P^T -> PlP (q4-crosslane redistribution via LDS) ----
#pragma unroll
        for (int js = 0; js < 2; ++js) {
            unsigned int wlo, whi;
            asm("v_cvt_pk_bf16_f32 %0, %1, %2" : "=v"(wlo) : "v"(p[js * 4 + 0]), "v"(p[js * 4 + 1]));
            asm("v_cvt_pk_bf16_f32 %0, %1, %2" : "=v"(whi) : "v"(p[js * 4 + 2]), "v"(p[js * 4 + 3]));
            uint2 wv; wv.x = wlo; wv.y = whi;
            *(uint2*)((char*)&PlP[wave][c][0] + js * 32 + q4 * 8) = wv;
        }
        const s16x8 pf = *(const s16x8*)&PlP[wave][c][q4 * 8];

        // ---- PV ----
        __builtin_amdgcn_s_setprio(1);
#pragma unroll
        for (int dt = 0; dt < 4; ++dt) {
            const s16x8 vf = *(const s16x8*)&VtL[bufc][dt * 16 + c][(q4 ^ (c & 3)) * 8];
            acc[dt] = __builtin_amdgcn_mfma_f32_16x16x32_bf16(vf, pf, acc[dt], 0, 0, 0);
        }
        __builtin_amdgcn_s_setprio(0);

        // ---- counted drain: DMA(t+1) done; seg(t+1) stays in flight ----
        asm volatile("s_waitcnt vmcnt(4)" ::: "memory");
        __builtin_amdgcn_s_barrier();
        __builtin_amdgcn_sched_barrier(0);
    };

    for (int o = 0; o < NT32 / 2; ++o) {
        body(2 * o + 0, 0, pgA, pgB);
        body(2 * o + 1, 1, pgB, pgA);
    }
    asm volatile("s_waitcnt vmcnt(0)" ::: "memory");   // drain tail clamped ops

    // ---- epilogue: reduce lsum over q4 groups, store ----
    lsum += __shfl_xor(lsum, 16, 64);
    lsum += __shfl_xor(lsum, 32, 64);
    {
        const float inv = 1.f / lsum;
        float* op = out + (size_t)iRow * RS + boff;
#pragma unroll
        for (int dt = 0; dt < 4; ++dt) {
            const f32x4 o = acc[dt] * inv;
            *(f32x4*)&op[dt * 16 + q4 * 4] = o;
        }
    }
}

extern "C" void kernel_launch(void* const* d_in, const int* in_sizes, int n_in,
                              void* d_out, int out_size, void* d_ws, size_t ws_size,
                              hipStream_t stream) {
    const float* q   = (const float*)d_in[0];
    const float* kh  = (const float*)d_in[1];
    const float* v   = (const float*)d_in[2];
    const float* kr  = (const float*)d_in[3];
    const float* se  = (const float*)d_in[4];
    const float* sm  = (const float*)d_in[5];
    const float* rwb = (const float*)d_in[6];
    const float* rrb = (const float*)d_in[7];
    const float* rsb = (const float*)d_in[8];
    const float* msk = (const float*)d_in[9];
    float* out = (float*)d_out;

    char* wsb = (char*)d_ws;   // needs 16.8 + 12.6 = 29.4 MB
    u16x4* segP = (u16x4*)wsb;
    unsigned short* Kp  = (unsigned short*)(wsb + SEGP_BYTES);
    unsigned short* Krp = (unsigned short*)(wsb + SEGP_BYTES + KT_BYTES);
    unsigned short* Vtp = (unsigned short*)(wsb + SEGP_BYTES + 2 * KT_BYTES);

    pack_all_kernel<<<1024 + NBN * NT32, 256, 0, stream>>>(sm, msk, kh, kr, v,
                                                           segP, Kp, Krp, Vtp);
    relattn_kernel<<<512, 256, 0, stream>>>(q, se, rwb, rrb, rsb, segP, Kp, Krp, Vtp, out);
}

// Round 15
// 56.102 us; speedup vs baseline: 1.2529x; 1.2529x over previous
//
#include <hip/hip_runtime.h>

#define QLEN 1024
#define KLEN 1024
#define BSZ 2
#define NHEAD 16
#define DHEAD 64
#define RS 2048            /* BSZ*NHEAD*DHEAD floats per seq row */
#define BLK_I 64
#define BLK_J 32
#define NT32 (KLEN / BLK_J)   /* 32 tiles per bn */
#define NBN (BSZ * NHEAD)

#define SC2f  0.18033688011112440f   /* 0.125 * log2(e) */
#define MBIGf 1.4426950408889634e30f /* 1e30 * log2(e)  */

#define SEGP_BYTES  16777216u                     /* 2*64*32 subtiles x 4KB */
#define KT_BYTES    ((size_t)NBN * NT32 * 4096)   /* 4 MiB per tensor */

typedef __attribute__((ext_vector_type(8))) short s16x8;
typedef __attribute__((ext_vector_type(8))) unsigned short u16x8;
typedef __attribute__((ext_vector_type(4))) unsigned short u16x4;
typedef __attribute__((ext_vector_type(4))) float f32x4;
typedef __attribute__((ext_vector_type(2))) float f32x2;

__device__ __forceinline__ unsigned short f2bf(float f) {
    union { float f; unsigned int u; } x; x.f = f;
    unsigned int r = x.u + 0x7fffu + ((x.u >> 16) & 1u);
    return (unsigned short)(r >> 16);
}
__device__ __forceinline__ float bf2f(unsigned short h) {
    union { unsigned int u; float f; } x; x.u = ((unsigned int)h) << 16;
    return x.f;
}

typedef const __attribute__((address_space(1))) unsigned int* gas_t;
typedef __attribute__((address_space(3))) unsigned int* las_t;
__device__ __forceinline__ void gl_lds16(const void* g, void* l) {
    __builtin_amdgcn_global_load_lds((gas_t)g, (las_t)l, 16, 0, 0);
}

// ---- fused pre-pass ---------------------------------------------------------
// blocks [0, 2048):    seg transpose-pack: per (b, istrip16, jt32) 4KB subtile
//   in wave-consumption order: u16 pos = k*512 + lane*8 holds the 16B that
//   lane (c=lane&15, q4=lane>>4) consumes as pg[k>>1][k&1]:
//   i = istrip*16 + c,  j = jt*32 + (k>>1)*16 + q4*4 + (k&1)*2 + {0,1}
// blocks [2048, 3072): pack Kh, Kr(+1), V^T as 4KB bf16 tiles (verbatim R13)
__global__ __launch_bounds__(256)
void pack_all_kernel(const float* __restrict__ segmat,
                     const float* __restrict__ mask,
                     const float* __restrict__ kh,
                     const float* __restrict__ kr,
                     const float* __restrict__ v,
                     unsigned short* __restrict__ segT,
                     unsigned short* __restrict__ Kp,
                     unsigned short* __restrict__ Krp,
                     unsigned short* __restrict__ Vtp)
{
    __shared__ float smS[16][32][4];   // seg branch: 8KB
    __shared__ float smM[16][33];      // seg branch: 2.1KB (padded)
    __shared__ float VT[32][65];       // kv branch: 8.3KB
    const int bid = blockIdx.x;
    const int tid = threadIdx.x;

    if (bid < 2048) {
        const int istrip = bid >> 5;
        const int jt     = bid & 31;
        const int ib     = istrip * 16;
        const int jb     = jt * 32;
        {   // coalesced stage: segmat rows (4 f32 per j: b0s0,b0s1,b1s0,b1s1)
            const int il = tid >> 4;
            const int j2 = (tid & 15) * 2;
            const float* sp = segmat + ((size_t)(ib + il) * KLEN + jb + j2) * 4;
            *(f32x4*)&smS[il][j2][0]     = *(const f32x4*)sp;
            *(f32x4*)&smS[il][j2 + 1][0] = *(const f32x4*)(sp + 4);
            const float* mp = mask + (size_t)(ib + il) * KLEN + jb + j2;
            smM[il][j2]     = mp[0] * MBIGf;
            smM[il][j2 + 1] = mp[1] * MBIGf;
        }
        __syncthreads();
        const int k  = tid >> 6;
        const int l  = tid & 63;
        const int q4 = l >> 4;
        const int il = l & 15;
        const int jl = (k >> 1) * 16 + q4 * 4 + (k & 1) * 2;
#pragma unroll
        for (int b = 0; b < 2; ++b) {
            u16x8 o;
#pragma unroll
            for (int e = 0; e < 2; ++e) {
                o[e * 4 + 0] = f2bf(smS[il][jl + e][b * 2]);
                o[e * 4 + 1] = f2bf(smS[il][jl + e][b * 2 + 1]);
                o[e * 4 + 2] = f2bf(smM[il][jl + e]);
                o[e * 4 + 3] = 0;
            }
            unsigned short* op = segT + ((size_t)(b * 64 + istrip) << 16)
                                 + (jt << 11) + tid * 8;
            *(u16x8*)op = o;
        }
    } else {
        const int blk = bid - 2048;               // bn*NT32 + jt
        const int bn  = blk >> 5;
        const int jt  = blk & (NT32 - 1);
        const int b   = bn & 1;
        const int n   = bn >> 1;
        const int boff = b * NHEAD * DHEAD + n * DHEAD;
        const int j0  = jt * BLK_J;

        {   // v tile -> LDS (coalesced): 32 j-rows x 64 d
            const int j  = tid >> 3;
            const int dq = (tid & 7) * 8;
            const float* vp = v + (size_t)(j0 + j) * RS + boff + dq;
#pragma unroll
            for (int e = 0; e < 8; ++e) VT[j][dq + e] = vp[e];
        }
        __syncthreads();

        const size_t tb = (size_t)blk * 2048;     // u16 units (4KB tiles)
        {   // K / Kr: 256 chunks of 16B; row = j (0..31), 8 chunks/row
            const int row = tid >> 3;
            const int ch  = (tid & 7) ^ (row & 7);
            u16x8 ok, orr;
            const float* hp = kh + (size_t)(j0 + row) * RS + boff + ch * 8;
            const float* rp = kr + (size_t)(j0 + row + 1) * RS + boff + ch * 8; // shift +1
#pragma unroll
            for (int e = 0; e < 8; ++e) { ok[e] = f2bf(hp[e]); orr[e] = f2bf(rp[e]); }
            *(u16x8*)&Kp [tb + (size_t)tid * 8] = ok;
            *(u16x8*)&Krp[tb + (size_t)tid * 8] = orr;
        }
        {   // V^T: 256 granules; row = d (0..63), 4 granules/row
            const int d  = tid >> 2;
            const int g  = tid & 3;
            const int ch = g ^ (d & 3);
            u16x8 ov;
#pragma unroll
            for (int e = 0; e < 8; ++e) ov[e] = f2bf(VT[ch * 8 + e][d]);
            *(u16x8*)&Vtp[tb + (size_t)tid * 8] = ov;
        }
    }
}

// ---- main: swapped-QK, 4 i-strip waves, BLK_J=32; coalesced seg subtiles ----
__global__ __launch_bounds__(256, 2)
void relattn_kernel(const float* __restrict__ q,
                    const float* __restrict__ segemb,
                    const float* __restrict__ rwb,
                    const float* __restrict__ rrb,
                    const float* __restrict__ rsb,
                    const unsigned short* __restrict__ segT,
                    const unsigned short* __restrict__ Kp,
                    const unsigned short* __restrict__ Krp,
                    const unsigned short* __restrict__ Vtp,
                    float* __restrict__ out)
{
    __shared__ unsigned short KhL[2][32][64];
    __shared__ unsigned short KrL[2][32][64];
    __shared__ unsigned short VtL[2][64][32];
    __shared__ unsigned short PlP[4][16][40];   // per-wave P^T xchg (5KB)

    // XCD swizzle (R13, kept): group 16 heads of one (b,i0) per XCD
    const int F = blockIdx.x;            // 512 blocks
    const int x = F & 7;
    const int k = F >> 3;                // 0..63
    const int g = (k >> 4) * 8 + x;      // (b,i0) group id, 4 groups per XCD
    const int i0 = (g >> 1) * BLK_I;
    const int b  = g & 1;
    const int n  = k & 15;
    const int bn = n * 2 + b;            // matches pack layout
    const int boff = b * NHEAD * DHEAD + n * DHEAD;

    const int tid  = threadIdx.x;
    const int wave = tid >> 6;
    const int lane = tid & 63;
    const int q4   = lane >> 4;
    const int c    = lane & 15;
    const int iRow = i0 + wave * 16 + c;

    // ---- Q fragments + in-lane ef0 ----
    s16x8 qwf[2], qrf[2];
    float e0, e1;
    {
        const float* qp = q + (size_t)iRow * RS + boff;
        float es0 = 0.f, es1 = 0.f;
#pragma unroll
        for (int kk = 0; kk < 2; ++kk) {
            const int off = kk * 32 + q4 * 8;
            const f32x4 q0 = *(const f32x4*)(qp + off);
            const f32x4 q1 = *(const f32x4*)(qp + off + 4);
            const f32x4 w0 = *(const f32x4*)(rwb + n * DHEAD + off);
            const f32x4 w1 = *(const f32x4*)(rwb + n * DHEAD + off + 4);
            const f32x4 r0 = *(const f32x4*)(rrb + n * DHEAD + off);
            const f32x4 r1 = *(const f32x4*)(rrb + n * DHEAD + off + 4);
            const f32x4 sa = *(const f32x4*)(segemb + n * DHEAD + off);
            const f32x4 sb = *(const f32x4*)(segemb + n * DHEAD + off + 4);
            const f32x4 ta = *(const f32x4*)(segemb + (NHEAD + n) * DHEAD + off);
            const f32x4 tb = *(const f32x4*)(segemb + (NHEAD + n) * DHEAD + off + 4);
            const f32x4 ra = *(const f32x4*)(rsb + n * DHEAD + off);
            const f32x4 rb = *(const f32x4*)(rsb + n * DHEAD + off + 4);
            s16x8 tw, tr;
#pragma unroll
            for (int e = 0; e < 4; ++e) {
                tw[e]     = (short)f2bf(q0[e] + w0[e]);
                tw[4 + e] = (short)f2bf(q1[e] + w1[e]);
                tr[e]     = (short)f2bf(q0[e] + r0[e]);
                tr[4 + e] = (short)f2bf(q1[e] + r1[e]);
                es0 += (q0[e] + ra[e]) * sa[e] + (q1[e] + rb[e]) * sb[e];
                es1 += (q0[e] + ra[e]) * ta[e] + (q1[e] + rb[e]) * tb[e];
            }
            qwf[kk] = tw; qrf[kk] = tr;
        }
        es0 += __shfl_xor(es0, 16, 64); es0 += __shfl_xor(es0, 32, 64);
        es1 += __shfl_xor(es1, 16, 64); es1 += __shfl_xor(es1, 32, 64);
        e0 = es0 * SC2f; e1 = es1 * SC2f;
    }

    const int tbase = bn * NT32;
    auto stage = [&](int jt, int buf) {
        const size_t toff = ((size_t)(tbase + jt)) << 12;
        const int go = tid * 16;
        const int lo = wave * 1024;
        gl_lds16((const char*)Kp  + toff + go, (char*)&KhL[buf][0][0] + lo);
        gl_lds16((const char*)Krp + toff + go, (char*)&KrL[buf][0][0] + lo);
        gl_lds16((const char*)Vtp + toff + go, (char*)&VtL[buf][0][0] + lo);
    };

    stage(0, 0);
    __syncthreads();

    float m = -INFINITY, lsum = 0.f;
    f32x4 acc[4];
#pragma unroll
    for (int dt = 0; dt < 4; ++dt) acc[dt] = (f32x4)0.f;

    // per-wave coalesced seg subtile base: (b, istrip = i0/16 + wave)
    const unsigned short* segW = segT + ((size_t)(b * 64 + (i0 >> 4) + wave) << 16);

    int cur = 0;
    for (int jt = 0; jt < NT32; ++jt) {
        if (jt + 1 < NT32) stage(jt + 1, cur ^ 1);   // DMA flies under compute

        // ---- seg/mask: 4 fully-coalesced 1KB wave-loads ----
        const unsigned short* st = segW + (jt << 11);
        u16x8 pg[2][2];
        pg[0][0] = *(const u16x8*)(st + lane * 8);
        pg[0][1] = *(const u16x8*)(st + 512 + lane * 8);
        pg[1][0] = *(const u16x8*)(st + 1024 + lane * 8);
        pg[1][1] = *(const u16x8*)(st + 1536 + lane * 8);

        // ---- S^T = (Kh Qw^T + Kr Qr^T): D[j][i], lane holds row i=c ----
        f32x4 sjT[2];
        sjT[0] = (f32x4)0.f; sjT[1] = (f32x4)0.f;
        __builtin_amdgcn_s_setprio(1);
#pragma unroll
        for (int kk = 0; kk < 2; ++kk)
#pragma unroll
            for (int js = 0; js < 2; ++js) {
                const int row = js * 16 + c;
                const int pcK = ((kk * 4 + q4) ^ (c & 7)) * 8;
                const s16x8 khf = *(const s16x8*)&KhL[cur][row][pcK];
                const s16x8 krf = *(const s16x8*)&KrL[cur][row][pcK];
                sjT[js] = __builtin_amdgcn_mfma_f32_16x16x32_bf16(khf, qwf[kk], sjT[js], 0, 0, 0);
                sjT[js] = __builtin_amdgcn_mfma_f32_16x16x32_bf16(krf, qrf[kk], sjT[js], 0, 0, 0);
            }
        __builtin_amdgcn_s_setprio(0);

        // ---- bias + lane-local online softmax ----
        float sc8[8];
#pragma unroll
        for (int js = 0; js < 2; ++js)
#pragma unroll
            for (int r = 0; r < 4; ++r) {
                const u16x8 g2 = pg[js][r >> 1];
                const int bb = (r & 1) * 4;
                sc8[js * 4 + r] = sjT[js][r] * SC2f
                                  + bf2f(g2[bb]) * e0 + bf2f(g2[bb + 1]) * e1
                                  - bf2f(g2[bb + 2]);
            }
        float mt = fmaxf(
            fmaxf(fmaxf(sc8[0], sc8[1]), fmaxf(sc8[2], sc8[3])),
            fmaxf(fmaxf(sc8[4], sc8[5]), fmaxf(sc8[6], sc8[7])));
        mt = fmaxf(mt, __shfl_xor(mt, 16, 64));
        mt = fmaxf(mt, __shfl_xor(mt, 32, 64));
        const float mn  = fmaxf(m, mt);
        const float scl = __builtin_amdgcn_exp2f(m - mn);
        m = mn;
#pragma unroll
        for (int dt = 0; dt < 4; ++dt) acc[dt] *= scl;
        float p[8], ps = 0.f;
#pragma unroll
        for (int e = 0; e < 8; ++e) {
            p[e] = __builtin_amdgcn_exp2f(sc8[e] - m);
            ps += p[e];
        }
        lsum = lsum * scl + ps;   // per-lane q4-partial; reduced at epilogue

        // ---- pack P^T -> PlP (q4-crosslane redistribution via LDS) ----
#pragma unroll
        for (int js = 0; js < 2; ++js) {
            unsigned int wlo, whi;
            asm("v_cvt_pk_bf16_f32 %0, %1, %2" : "=v"(wlo) : "v"(p[js * 4 + 0]), "v"(p[js * 4 + 1]));
            asm("v_cvt_pk_bf16_f32 %0, %1, %2" : "=v"(whi) : "v"(p[js * 4 + 2]), "v"(p[js * 4 + 3]));
            uint2 wv; wv.x = wlo; wv.y = whi;
            *(uint2*)((char*)&PlP[wave][c][0] + js * 32 + q4 * 8) = wv;
        }
        const s16x8 pf = *(const s16x8*)&PlP[wave][c][q4 * 8];

        // ---- PV: acc^T[d][i] += V^T(16d x 32j) * P^T(32j x 16i) ----
        __builtin_amdgcn_s_setprio(1);
#pragma unroll
        for (int dt = 0; dt < 4; ++dt) {
            const s16x8 vf = *(const s16x8*)&VtL[cur][dt * 16 + c][(q4 ^ (c & 3)) * 8];
            acc[dt] = __builtin_amdgcn_mfma_f32_16x16x32_bf16(vf, pf, acc[dt], 0, 0, 0);
        }
        __builtin_amdgcn_s_setprio(0);

        __syncthreads();   // drains DMA + all waves done with buf[cur]
        cur ^= 1;
    }

    // ---- full-row lsum (reduce over q4 groups) ----
    lsum += __shfl_xor(lsum, 16, 64);
    lsum += __shfl_xor(lsum, 32, 64);

    // ---- store (wave owns full j-range of its rows) ----
    {
        const float inv = 1.f / lsum;
        float* op = out + (size_t)iRow * RS + boff;
#pragma unroll
        for (int dt = 0; dt < 4; ++dt) {
            const f32x4 o = acc[dt] * inv;
            *(f32x4*)&op[dt * 16 + q4 * 4] = o;
        }
    }
}

extern "C" void kernel_launch(void* const* d_in, const int* in_sizes, int n_in,
                              void* d_out, int out_size, void* d_ws, size_t ws_size,
                              hipStream_t stream) {
    const float* q   = (const float*)d_in[0];
    const float* kh  = (const float*)d_in[1];
    const float* v   = (const float*)d_in[2];
    const float* kr  = (const float*)d_in[3];
    const float* se  = (const float*)d_in[4];
    const float* sm  = (const float*)d_in[5];
    const float* rwb = (const float*)d_in[6];
    const float* rrb = (const float*)d_in[7];
    const float* rsb = (const float*)d_in[8];
    const float* msk = (const float*)d_in[9];
    float* out = (float*)d_out;

    char* wsb = (char*)d_ws;   // needs 16.8 + 12.6 = 29.4 MB
    unsigned short* segT = (unsigned short*)wsb;
    unsigned short* Kp   = (unsigned short*)(wsb + SEGP_BYTES);
    unsigned short* Krp  = (unsigned short*)(wsb + SEGP_BYTES + KT_BYTES);
    unsigned short* Vtp  = (unsigned short*)(wsb + SEGP_BYTES + 2 * KT_BYTES);

    pack_all_kernel<<<2048 + NBN * NT32, 256, 0, stream>>>(sm, msk, kh, kr, v,
                                                           segT, Kp, Krp, Vtp);
    relattn_kernel<<<512, 256, 0, stream>>>(q, se, rwb, rrb, rsb, segT, Kp, Krp, Vtp, out);
}